// Round 12
// baseline (179.338 us; speedup 1.0000x reference)
//
#include <hip/hip_runtime.h>
#include <hip/hip_bf16.h>

#define HH 512
#define WW 640
#define HW (HH*WW)
#define NT 256
#define IMPLANEP (432*8 + 8)    // img plane stride in shorts (36x12 pix, +16B pad)
#define H1PLANEP (360*8 + 8)    // h1 plane stride in shorts (36x10 pix, +16B pad)

typedef short short8  __attribute__((ext_vector_type(8)));
typedef short short4v __attribute__((ext_vector_type(4)));
typedef float f32x16  __attribute__((ext_vector_type(16)));
typedef float f32x4   __attribute__((ext_vector_type(4)));

__device__ inline short f2bf(float f) {
    __hip_bfloat16 h = __float2bfloat16(f);
    short s; __builtin_memcpy(&s, &h, 2);
    return s;
}

// ---- prep: fold BN into w1, bias as 10th tap row, transpose to MFMA layouts ----
__global__ void prep_weights(const float* __restrict__ w1, const float* __restrict__ b1,
                             const float* __restrict__ gamma, const float* __restrict__ beta,
                             const float* __restrict__ rmean, const float* __restrict__ rvar,
                             const float* __restrict__ w2,
                             short* __restrict__ ws_w1, short* __restrict__ ws_w2)
{
    int tid = blockIdx.x*blockDim.x + threadIdx.x;
    int stride = gridDim.x*blockDim.x;
    for (int i = tid; i < 4608; i += stride) {          // w1: [oc][c][t] -> [t][oc32][c16] * A_oc
        int oc = i / 144, rem = i - oc*144, c = rem / 9, t = rem - c*9;
        float a = gamma[oc] * rsqrtf(rvar[oc] + 1e-5f);
        ws_w1[t*512 + oc*16 + c] = f2bf(w1[i] * a);
    }
    for (int i = tid; i < 512; i += stride) {           // tap 9 = bias row (c==0 one-hot)
        int oc = i >> 4, c = i & 15;
        float a = gamma[oc] * rsqrtf(rvar[oc] + 1e-5f);
        float bias = beta[oc] + (b1[oc] - rmean[oc]) * a;
        ws_w1[9*512 + i] = (c == 0) ? f2bf(bias) : (short)0;
    }
    for (int i = tid; i < 4608; i += stride) {          // w2: [f][c][t] -> [t][f16][c32], f>=9 zero
        int t = i >> 9, f = (i >> 5) & 15, c = i & 31;
        float val = (f < 9) ? w2[(f*32 + c)*9 + t] : 0.f;
        ws_w2[i] = f2bf(val);
    }
}

// ---- persistent fused kernel: 1024 blocks x 5 tiles, late-issued reg prefetch ----
__launch_bounds__(NT, 4)
__global__ void fastprop_main(const float* __restrict__ depth,
                              const float* __restrict__ img,
                              const short* __restrict__ ws_w1,
                              const short* __restrict__ ws_w2,
                              float* __restrict__ out)
{
    __shared__ short s_img[2*IMPLANEP];   // [ch-plane][pix 36x12][8ch] bf16
    __shared__ short s_h1 [4*H1PLANEP];   // [ch-plane][pix 36x10][8ch] bf16
    __shared__ float s_depth[340];        // 34x10 replicate-clamped fp32

    const int tid  = threadIdx.x;
    const int lane = tid & 63;
    const int wid  = tid >> 6;

    // 1024 blocks = 8 XCDs x 128; each owns 5 consecutive tiles (halo-adjacent)
    const int nid      = blockIdx.x;
    const int base_oid = (nid & 7)*640 + (nid >> 3)*5;

    float r[4][8]; float msk[4]; float pd0, pd1;

    auto issue = [&](int oid) {
        int bz = oid / 1280, rm = oid - bz*1280;
        int by = rm / 20,    bx = rm - by*20;
        int gy0 = by*8, gx0 = bx*32;
        const float* imgb = img   + (size_t)bz*16*HW;
        const float* dpb  = depth + (size_t)bz*HW;
        #pragma unroll
        for (int j = 0; j < 4; ++j) {
            int g = tid + j*NT; g = g > 863 ? 863 : g;      // clamp (dup load, write-masked)
            int pixel = g >> 1, half = g & 1;
            int iy = pixel / 36, ix = pixel - 36*(pixel/36);
            int gy = gy0 + iy - 2, gx = gx0 + ix - 2;
            bool v = ((unsigned)gy < HH) && ((unsigned)gx < WW);
            int cy = min(max(gy, 0), HH-1), cx = min(max(gx, 0), WW-1);
            const float* p = imgb + (size_t)(half*8)*HW + cy*WW + cx;
            msk[j] = v ? 1.f : 0.f;
            #pragma unroll
            for (int c = 0; c < 8; ++c) r[j][c] = p[c*HW];
        }
        {
            int ty = tid / 34, tx = tid - 34*(tid/34);
            pd0 = dpb[min(max(gy0 + ty - 1, 0), HH-1)*WW + min(max(gx0 + tx - 1, 0), WW-1)];
            int i1 = tid + 256; i1 = i1 > 339 ? 339 : i1;
            ty = i1 / 34; tx = i1 - 34*ty;
            pd1 = dpb[min(max(gy0 + ty - 1, 0), HH-1)*WW + min(max(gx0 + tx - 1, 0), WW-1)];
        }
    };

    issue(base_oid);   // prologue prefetch

    for (int t = 0; t < 5; ++t) {
        const int oid = base_oid + t;
        int bz = oid / 1280, rm = oid - bz*1280;
        int by = rm / 20,    bx = rm - by*20;
        const int gy0 = by*8, gx0 = bx*32;

        __syncthreads();   // vmcnt(0) drain lands HERE -> prefetch arrived; prev tile done

        // ---- dump prefetched regs -> LDS (mask, f2bf, pack) ----
        #pragma unroll
        for (int j = 0; j < 4; ++j) {
            int g = tid + j*NT;
            if (g < 864) {
                short8 vv;
                #pragma unroll
                for (int c = 0; c < 8; ++c) vv[c] = f2bf(msk[j] * r[j][c]);
                *(short8*)&s_img[(g & 1)*IMPLANEP + (g >> 1)*8] = vv;
            }
        }
        s_depth[tid] = pd0;
        if (tid < 84) s_depth[tid + 256] = pd1;

        __syncthreads();   // staging visible (no vmem outstanding -> cheap drain)

        // ---- conv1 (32x32x16 MFMA, 9 taps + bias tap) -> s_h1 channel-planes ----
        {
            const int oc = lane & 31, cg = lane >> 5;
            short8 a1[10];
            #pragma unroll
            for (int tt = 0; tt < 10; ++tt)
                a1[tt] = *(const short8*)&ws_w1[tt*512 + oc*16 + cg*8];
            short8 bb = (short8)0;               // bias-tap B: one-hot 1.0 at k==0
            bb[0] = (cg == 0) ? (short)0x3F80 : (short)0;

            const int OFS1[9] = {0, 8, 16, 288, 296, 304, 576, 584, 592};
            const int px = lane & 31;

            #pragma unroll
            for (int gi = 0; gi < 3; ++gi) {
                int g    = wid + gi*4;
                int hp   = g*32 + px;
                int base = cg*IMPLANEP + hp*8;
                f32x16 acc;
                #pragma unroll
                for (int i = 0; i < 16; ++i) acc[i] = 0.f;
                acc = __builtin_amdgcn_mfma_f32_32x32x16_bf16(a1[9], bb, acc, 0, 0, 0);
                #pragma unroll
                for (int tt = 0; tt < 9; ++tt)
                    acc = __builtin_amdgcn_mfma_f32_32x32x16_bf16(
                             a1[tt], *(const short8*)&s_img[base + OFS1[tt]], acc, 0, 0, 0);

                if (hp < 360) {
                    unsigned hy = (unsigned)hp / 36u;
                    int hx = hp - (int)hy*36;
                    int gy = gy0 + (int)hy - 1, gx = gx0 + hx - 1;
                    bool inb = ((unsigned)gy < HH) && ((unsigned)gx < WW);
                    #pragma unroll
                    for (int q = 0; q < 4; ++q) {      // plane q = channels 8q..8q+7
                        short4v h;
                        #pragma unroll
                        for (int j = 0; j < 4; ++j) {
                            float hv = fmaxf(acc[q*4 + j], 0.f);
                            h[j] = inb ? f2bf(hv) : (short)0;
                        }
                        *(short4v*)&s_h1[q*H1PLANEP + hp*8 + 4*cg] = h;
                    }
                }
            }
        }
        __syncthreads();   // h1 visible (no vmem outstanding -> cheap drain)

        if (t < 4) issue(oid + 1);   // loads fly during conv2; drained at next loop-top

        // ---- conv2 (16x16x32 MFMA) rolling 2-row window + softmax + gather ----
        {
            const int fl = lane & 15, cg2 = lane >> 4;
            short8 a2[9];
            #pragma unroll
            for (int tt = 0; tt < 9; ++tt)
                a2[tt] = *(const short8*)&ws_w2[tt*512 + fl*32 + cg2*8];

            const int r0 = 2*wid;                // this wave's output rows r0, r0+1

            #pragma unroll
            for (int chh = 0; chh < 2; ++chh) {  // column halves 0-15, 16-31
                const int ox0 = chh*16;
                const int colbase = cg2*H1PLANEP + (ox0 + fl)*8;

                f32x4 acc0, acc1;
                #pragma unroll
                for (int i = 0; i < 4; ++i) { acc0[i] = 0.f; acc1[i] = 0.f; }

                short8 Ra[3], Rb[3];             // rolling 2-row fragment window
                #pragma unroll
                for (int dx = 0; dx < 3; ++dx)
                    Ra[dx] = *(const short8*)&s_h1[colbase + ((r0 + 0)*36 + dx)*8];
                #pragma unroll
                for (int dx = 0; dx < 3; ++dx)
                    acc0 = __builtin_amdgcn_mfma_f32_16x16x32_bf16(a2[dx], Ra[dx], acc0, 0, 0, 0);
                #pragma unroll
                for (int dx = 0; dx < 3; ++dx)
                    Rb[dx] = *(const short8*)&s_h1[colbase + ((r0 + 1)*36 + dx)*8];
                #pragma unroll
                for (int dx = 0; dx < 3; ++dx) {
                    acc0 = __builtin_amdgcn_mfma_f32_16x16x32_bf16(a2[3 + dx], Rb[dx], acc0, 0, 0, 0);
                    acc1 = __builtin_amdgcn_mfma_f32_16x16x32_bf16(a2[dx],     Rb[dx], acc1, 0, 0, 0);
                }
                #pragma unroll
                for (int dx = 0; dx < 3; ++dx)
                    Ra[dx] = *(const short8*)&s_h1[colbase + ((r0 + 2)*36 + dx)*8];
                #pragma unroll
                for (int dx = 0; dx < 3; ++dx) {
                    acc0 = __builtin_amdgcn_mfma_f32_16x16x32_bf16(a2[6 + dx], Ra[dx], acc0, 0, 0, 0);
                    acc1 = __builtin_amdgcn_mfma_f32_16x16x32_bf16(a2[3 + dx], Ra[dx], acc1, 0, 0, 0);
                }
                #pragma unroll
                for (int dx = 0; dx < 3; ++dx)
                    Rb[dx] = *(const short8*)&s_h1[colbase + ((r0 + 3)*36 + dx)*8];
                #pragma unroll
                for (int dx = 0; dx < 3; ++dx)
                    acc1 = __builtin_amdgcn_mfma_f32_16x16x32_bf16(a2[6 + dx], Rb[dx], acc1, 0, 0, 0);

                #pragma unroll
                for (int rr = 0; rr < 2; ++rr) {
                    f32x4 lg = rr ? acc1 : acc0;
                    int oy = r0 + rr, ox = ox0 + fl;
                    float num = 0.f, den = 0.f;
                    #pragma unroll
                    for (int q = 0; q < 4; ++q) {
                        int f = cg2*4 + q;           // conv2 output channel
                        if (f < 9) {
                            float e = __expf(lg[q]);
                            int fy = f/3, fx = f - fy*3;
                            float d = s_depth[(oy + fy)*34 + (ox + fx)];
                            den += e; num += e * d;
                        }
                    }
                    num += __shfl_xor(num, 16); den += __shfl_xor(den, 16);
                    num += __shfl_xor(num, 32); den += __shfl_xor(den, 32);
                    if (cg2 == 0)
                        out[(size_t)bz*HW + (size_t)(gy0 + oy)*WW + (gx0 + ox)] = num / den;
                }
            }
        }
    }
}

extern "C" void kernel_launch(void* const* d_in, const int* in_sizes, int n_in,
                              void* d_out, int out_size, void* d_ws, size_t ws_size,
                              hipStream_t stream) {
    const float* depth = (const float*)d_in[0];
    const float* img   = (const float*)d_in[1];
    const float* w1    = (const float*)d_in[2];
    const float* b1    = (const float*)d_in[3];
    const float* gamma = (const float*)d_in[4];
    const float* beta  = (const float*)d_in[5];
    const float* rmean = (const float*)d_in[6];
    const float* rvar  = (const float*)d_in[7];
    const float* w2    = (const float*)d_in[8];
    float* out = (float*)d_out;

    short* ws_w1 = (short*)d_ws;          // 5120 shorts (10 taps x 512)
    short* ws_w2 = ws_w1 + 5120;          // 4608 shorts

    prep_weights<<<16, 256, 0, stream>>>(w1, b1, gamma, beta, rmean, rvar, w2,
                                         ws_w1, ws_w2);
    fastprop_main<<<1024, NT, 0, stream>>>(depth, img, ws_w1, ws_w2, out);
}

// Round 13
// 123.490 us; speedup vs baseline: 1.4522x; 1.4522x over previous
//
#include <hip/hip_runtime.h>
#include <hip/hip_bf16.h>

#define HH 512
#define WW 640
#define HW (HH*WW)
#define NT 512
#define NTILES 5
#define IMPLANEP (432*8 + 8)    // img plane stride in shorts (36x12 pix, +16B pad)
#define H1PLANEP (360*8 + 8)    // h1 plane stride in shorts (36x10 pix, +16B pad)

typedef short short8  __attribute__((ext_vector_type(8)));
typedef short short4v __attribute__((ext_vector_type(4)));
typedef float f32x16  __attribute__((ext_vector_type(16)));
typedef float f32x4   __attribute__((ext_vector_type(4)));

__device__ inline short f2bf(float f) {
    __hip_bfloat16 h = __float2bfloat16(f);
    short s; __builtin_memcpy(&s, &h, 2);
    return s;
}

// ---- prep: fold BN into w1, bias as 10th tap row, transpose to MFMA layouts ----
__global__ void prep_weights(const float* __restrict__ w1, const float* __restrict__ b1,
                             const float* __restrict__ gamma, const float* __restrict__ beta,
                             const float* __restrict__ rmean, const float* __restrict__ rvar,
                             const float* __restrict__ w2,
                             short* __restrict__ ws_w1, short* __restrict__ ws_w2)
{
    int tid = blockIdx.x*blockDim.x + threadIdx.x;
    int stride = gridDim.x*blockDim.x;
    for (int i = tid; i < 4608; i += stride) {          // w1: [oc][c][t] -> [t][oc32][c16] * A_oc
        int oc = i / 144, rem = i - oc*144, c = rem / 9, t = rem - c*9;
        float a = gamma[oc] * rsqrtf(rvar[oc] + 1e-5f);
        ws_w1[t*512 + oc*16 + c] = f2bf(w1[i] * a);
    }
    for (int i = tid; i < 512; i += stride) {           // tap 9 = bias row (c==0 one-hot)
        int oc = i >> 4, c = i & 15;
        float a = gamma[oc] * rsqrtf(rvar[oc] + 1e-5f);
        float bias = beta[oc] + (b1[oc] - rmean[oc]) * a;
        ws_w1[9*512 + i] = (c == 0) ? f2bf(bias) : (short)0;
    }
    for (int i = tid; i < 4608; i += stride) {          // w2: [f][c][t] -> [t][f16][c32], f>=9 zero
        int t = i >> 9, f = (i >> 5) & 15, c = i & 31;
        float val = (f < 9) ? w2[(f*32 + c)*9 + t] : 0.f;
        ws_w2[i] = f2bf(val);
    }
}

__device__ __forceinline__ void stage_granule(const float* __restrict__ imgb,
                                              int gy0, int gx0,
                                              short* __restrict__ simgbuf, int g)
{
    int pixel = g >> 1, half = g & 1;
    int iy = pixel / 36, ix = pixel - 36*iy;
    int gy = gy0 + iy - 2, gx = gx0 + ix - 2;
    bool v = ((unsigned)gy < HH) && ((unsigned)gx < WW);
    int cy = min(max(gy, 0), HH-1), cx = min(max(gx, 0), WW-1);
    const float* p = imgb + (size_t)(half*8)*HW + cy*WW + cx;
    float m = v ? 1.f : 0.f;
    short8 vv;
    #pragma unroll
    for (int c = 0; c < 8; ++c) vv[c] = f2bf(m * p[c*HW]);
    *(short8*)&simgbuf[half*IMPLANEP + pixel*8] = vv;
}

// ---- persistent wave-specialized kernel: 4 compute waves + 4 stager waves ----
__launch_bounds__(NT, 2)
__global__ void fastprop_main(const float* __restrict__ depth,
                              const float* __restrict__ img,
                              const short* __restrict__ ws_w1,
                              const short* __restrict__ ws_w2,
                              float* __restrict__ out)
{
    __shared__ short s_img[2][2*IMPLANEP];  // ping-pong img tile (2 x 13856 B)
    __shared__ short s_h1 [4*H1PLANEP];     // h1 channel-planes (23104 B)
    __shared__ float s_depth[2][340];       // ping-pong depth tile (2 x 1360 B)

    const int tid  = threadIdx.x;
    const int lane = tid & 63;
    const int wid  = tid >> 6;

    // 1024 blocks = 8 XCDs x 128; each owns 5 consecutive tiles (halo-adjacent)
    const int nid      = blockIdx.x;
    const int base_oid = (nid & 7)*640 + (nid >> 3)*NTILES;

    // ---- prologue: all 8 waves stage tile 0 into buffer 0 ----
    {
        int bz = base_oid / 1280, rm = base_oid - bz*1280;
        int by = rm / 20, bx = rm - 20*by;
        int gy0 = by*8, gx0 = bx*32;
        const float* imgb = img   + (size_t)bz*16*HW;
        const float* dpb  = depth + (size_t)bz*HW;
        for (int g = tid; g < 864; g += NT)
            stage_granule(imgb, gy0, gx0, s_img[0], g);
        if (tid < 340) {
            int ty = tid / 34, tx = tid - 34*ty;
            s_depth[0][tid] = dpb[min(max(gy0 + ty - 1, 0), HH-1)*WW
                                  + min(max(gx0 + tx - 1, 0), WW-1)];
        }
    }
    __syncthreads();

    for (int t = 0; t < NTILES; ++t) {
        const int oid = base_oid + t;
        int bz = oid / 1280, rm = oid - bz*1280;
        int by = rm / 20, bx = rm - 20*by;
        const int gy0 = by*8, gx0 = bx*32;
        const int cur = t & 1, nxt = cur ^ 1;

        // next-tile origin (for stager waves)
        int bz2 = 0, gy02 = 0, gx02 = 0;
        const bool have_next = (t + 1 < NTILES);
        if (have_next) {
            int o2 = oid + 1;
            bz2 = o2 / 1280; int r2 = o2 - bz2*1280;
            int by2 = r2 / 20, bx2 = r2 - 20*by2;
            gy02 = by2*8; gx02 = bx2*32;
        }
        const float* imgb2 = img   + (size_t)bz2*16*HW;
        const float* dpb2  = depth + (size_t)bz2*HW;
        const int st = tid - 256;

        // ================= window 1: conv1 || stage(next, first half) =================
        if (wid < 4) {
            const int oc = lane & 31, cg = lane >> 5;
            short8 a1[10];
            #pragma unroll
            for (int tt = 0; tt < 10; ++tt)
                a1[tt] = *(const short8*)&ws_w1[tt*512 + oc*16 + cg*8];
            short8 bb = (short8)0;               // bias-tap B: one-hot 1.0 at k==0
            bb[0] = (cg == 0) ? (short)0x3F80 : (short)0;

            const int OFS1[9] = {0, 8, 16, 288, 296, 304, 576, 584, 592};
            const int px = lane & 31;

            #pragma unroll
            for (int gi = 0; gi < 3; ++gi) {
                int g    = wid + gi*4;
                int hp   = g*32 + px;
                int base = cg*IMPLANEP + hp*8;
                f32x16 acc;
                #pragma unroll
                for (int i = 0; i < 16; ++i) acc[i] = 0.f;
                acc = __builtin_amdgcn_mfma_f32_32x32x16_bf16(a1[9], bb, acc, 0, 0, 0);
                #pragma unroll
                for (int tt = 0; tt < 9; ++tt)
                    acc = __builtin_amdgcn_mfma_f32_32x32x16_bf16(
                             a1[tt], *(const short8*)&s_img[cur][base + OFS1[tt]], acc, 0, 0, 0);

                if (hp < 360) {
                    unsigned hy = (unsigned)hp / 36u;
                    int hx = hp - (int)hy*36;
                    int gy = gy0 + (int)hy - 1, gx = gx0 + hx - 1;
                    bool inb = ((unsigned)gy < HH) && ((unsigned)gx < WW);
                    #pragma unroll
                    for (int q = 0; q < 4; ++q) {      // plane q = channels 8q..8q+7
                        short4v h;
                        #pragma unroll
                        for (int j = 0; j < 4; ++j) {
                            float hv = fmaxf(acc[q*4 + j], 0.f);
                            h[j] = inb ? f2bf(hv) : (short)0;
                        }
                        *(short4v*)&s_h1[q*H1PLANEP + hp*8 + 4*cg] = h;
                    }
                }
            }
        } else if (have_next) {
            stage_granule(imgb2, gy02, gx02, s_img[nxt], st);
            if (st < 176) stage_granule(imgb2, gy02, gx02, s_img[nxt], st + 256);
        }
        __syncthreads();   // h1 visible; stage half-1 done

        // ================= window 2: conv2+store || stage(next, second half) =================
        if (wid < 4) {
            const int fl = lane & 15, cg2 = lane >> 4;
            short8 a2[9];
            #pragma unroll
            for (int tt = 0; tt < 9; ++tt)
                a2[tt] = *(const short8*)&ws_w2[tt*512 + fl*32 + cg2*8];

            const int r0 = 2*wid;                // this wave's output rows r0, r0+1

            #pragma unroll
            for (int chh = 0; chh < 2; ++chh) {  // column halves 0-15, 16-31
                const int ox0 = chh*16;
                const int colbase = cg2*H1PLANEP + (ox0 + fl)*8;

                short8 F[4][3];                  // h1 rows r0..r0+3, dx 0..2
                #pragma unroll
                for (int i = 0; i < 4; ++i)
                    #pragma unroll
                    for (int dx = 0; dx < 3; ++dx)
                        F[i][dx] = *(const short8*)&s_h1[colbase + ((r0 + i)*36 + dx)*8];

                f32x4 acc0, acc1;
                #pragma unroll
                for (int i = 0; i < 4; ++i) { acc0[i] = 0.f; acc1[i] = 0.f; }
                #pragma unroll
                for (int i = 0; i < 3; ++i)
                    #pragma unroll
                    for (int dx = 0; dx < 3; ++dx)
                        acc0 = __builtin_amdgcn_mfma_f32_16x16x32_bf16(
                                 a2[i*3 + dx], F[i][dx], acc0, 0, 0, 0);
                #pragma unroll
                for (int i = 0; i < 3; ++i)
                    #pragma unroll
                    for (int dx = 0; dx < 3; ++dx)
                        acc1 = __builtin_amdgcn_mfma_f32_16x16x32_bf16(
                                 a2[i*3 + dx], F[i + 1][dx], acc1, 0, 0, 0);

                #pragma unroll
                for (int rr = 0; rr < 2; ++rr) {
                    f32x4 lg = rr ? acc1 : acc0;
                    int oy = r0 + rr, ox = ox0 + fl;
                    float num = 0.f, den = 0.f;
                    #pragma unroll
                    for (int q = 0; q < 4; ++q) {
                        int f = cg2*4 + q;           // conv2 output channel
                        if (f < 9) {
                            float e = __expf(lg[q]);
                            int fy = f/3, fx = f - fy*3;
                            float d = s_depth[cur][(oy + fy)*34 + (ox + fx)];
                            den += e; num += e * d;
                        }
                    }
                    num += __shfl_xor(num, 16); den += __shfl_xor(den, 16);
                    num += __shfl_xor(num, 32); den += __shfl_xor(den, 32);
                    if (cg2 == 0)
                        out[(size_t)bz*HW + (size_t)(gy0 + oy)*WW + (gx0 + ox)] = num / den;
                }
            }
        } else if (have_next) {
            stage_granule(imgb2, gy02, gx02, s_img[nxt], 432 + st);
            if (st < 176) stage_granule(imgb2, gy02, gx02, s_img[nxt], 688 + st);
            {
                int ty = st / 34, tx = st - 34*ty;
                s_depth[nxt][st] = dpb2[min(max(gy02 + ty - 1, 0), HH-1)*WW
                                        + min(max(gx02 + tx - 1, 0), WW-1)];
            }
            if (st < 84) {
                int i1 = st + 256;
                int ty = i1 / 34, tx = i1 - 34*ty;
                s_depth[nxt][i1] = dpb2[min(max(gy02 + ty - 1, 0), HH-1)*WW
                                        + min(max(gx02 + tx - 1, 0), WW-1)];
            }
        }
        __syncthreads();   // stage complete; conv2 done reading s_h1/s_depth[cur]
    }
}

extern "C" void kernel_launch(void* const* d_in, const int* in_sizes, int n_in,
                              void* d_out, int out_size, void* d_ws, size_t ws_size,
                              hipStream_t stream) {
    const float* depth = (const float*)d_in[0];
    const float* img   = (const float*)d_in[1];
    const float* w1    = (const float*)d_in[2];
    const float* b1    = (const float*)d_in[3];
    const float* gamma = (const float*)d_in[4];
    const float* beta  = (const float*)d_in[5];
    const float* rmean = (const float*)d_in[6];
    const float* rvar  = (const float*)d_in[7];
    const float* w2    = (const float*)d_in[8];
    float* out = (float*)d_out;

    short* ws_w1 = (short*)d_ws;          // 5120 shorts (10 taps x 512)
    short* ws_w2 = ws_w1 + 5120;          // 4608 shorts

    prep_weights<<<16, 256, 0, stream>>>(w1, b1, gamma, beta, rmean, rvar, w2,
                                         ws_w1, ws_w2);
    fastprop_main<<<1024, NT, 0, stream>>>(depth, img, ws_w1, ws_w2, out);
}

// Round 14
// 71.774 us; speedup vs baseline: 2.4986x; 1.7205x over previous
//
#include <hip/hip_runtime.h>
#include <hip/hip_bf16.h>

#define HH 512
#define WW 640
#define HW (HH*WW)
#define NT 256
#define NTILES 5
#define IMPLANE 3456            // shorts per bf16 img plane (432 px x 8 ch)
#define H1PLANE 2728            // shorts per h1 plane (340 px x 8 + 8 pad)

typedef short short8  __attribute__((ext_vector_type(8)));
typedef short short4v __attribute__((ext_vector_type(4)));
typedef float f32x16  __attribute__((ext_vector_type(16)));
typedef float f32x4   __attribute__((ext_vector_type(4)));

__device__ inline short f2bf(float f) {
    __hip_bfloat16 h = __float2bfloat16(f);
    short s; __builtin_memcpy(&s, &h, 2);
    return s;
}

// ---- prep: fold BN into w1, bias as 10th tap row, transpose to MFMA layouts ----
__global__ void prep_weights(const float* __restrict__ w1, const float* __restrict__ b1,
                             const float* __restrict__ gamma, const float* __restrict__ beta,
                             const float* __restrict__ rmean, const float* __restrict__ rvar,
                             const float* __restrict__ w2,
                             short* __restrict__ ws_w1, short* __restrict__ ws_w2)
{
    int tid = blockIdx.x*blockDim.x + threadIdx.x;
    int stride = gridDim.x*blockDim.x;
    for (int i = tid; i < 4608; i += stride) {          // w1: [oc][c][t] -> [t][oc32][c16] * A_oc
        int oc = i / 144, rem = i - oc*144, c = rem / 9, t = rem - c*9;
        float a = gamma[oc] * rsqrtf(rvar[oc] + 1e-5f);
        ws_w1[t*512 + oc*16 + c] = f2bf(w1[i] * a);
    }
    for (int i = tid; i < 512; i += stride) {           // tap 9 = bias row (c==0 one-hot)
        int oc = i >> 4, c = i & 15;
        float a = gamma[oc] * rsqrtf(rvar[oc] + 1e-5f);
        float bias = beta[oc] + (b1[oc] - rmean[oc]) * a;
        ws_w1[9*512 + i] = (c == 0) ? f2bf(bias) : (short)0;
    }
    for (int i = tid; i < 4608; i += stride) {          // w2: [f][c][t] -> [t][f16][c32], f>=9 zero
        int t = i >> 9, f = (i >> 5) & 15, c = i & 31;
        float val = (f < 9) ? w2[(f*32 + c)*9 + t] : 0.f;
        ws_w2[i] = f2bf(val);
    }
}

// ---- fused persistent kernel: fp32 tile via global_load_lds, in-LDS convert ----
__launch_bounds__(NT, 4)
__global__ void fastprop_main(const float* __restrict__ depth,
                              const float* __restrict__ img,
                              const short* __restrict__ ws_w1,
                              const short* __restrict__ ws_w2,
                              float* __restrict__ out)
{
    __shared__ float s_buf[6912];        // 27648 B: fp32 [c16][px432]; bf16 img overlaid on c0-7
    __shared__ short s_h1[4*H1PLANE];    // 21824 B: [plane4][340 px][8ch]
    __shared__ float s_depth[2][340];    //  2720 B: ping-pong 34x10

    short* s_img = (short*)s_buf;        // bf16 [plane2][px432][8ch], plane stride 3456

    const int tid  = threadIdx.x;
    const int lane = tid & 63;
    const int wid  = tid >> 6;

    // 1024 blocks = 8 XCDs x 128; 5 consecutive bx tiles, same (bz, by)
    const int nid  = blockIdx.x;
    const int base = (nid & 7)*640 + (nid >> 3)*NTILES;
    const int bz   = base / 1280;
    const int rm   = base - bz*1280;
    const int by   = rm / 20;
    const int bx0  = rm - by*20;
    const int gy0  = by*8;

    const float* imgb = img   + (size_t)bz*16*HW;
    const float* dpb  = depth + (size_t)bz*HW;

    // ---- tile-invariant DMA source offsets (y pre-clamped; x added per tile) ----
    int PRE[7];
    #pragma unroll
    for (int i = 0; i < 7; ++i) {
        int k = wid + 4*i;
        int s = k*64 + lane; s = s > 1727 ? 1727 : s;
        int c = s / 108, sc = s - c*108;
        int r = sc / 9,  ix0 = (sc - r*9)*4;
        int cy = min(max(gy0 + r - 2, 0), HH-1);
        PRE[i] = c*HW + cy*WW + ix0 - 2;
    }
    int PRED[2];
    #pragma unroll
    for (int i = 0; i < 2; ++i) {
        int k = wid + 4*i;
        int s = k*64 + lane; s = s > 339 ? 339 : s;
        int ty = s / 34, tx = s - ty*34;
        int cy = min(max(gy0 + ty - 1, 0), HH-1);
        PRED[i] = cy*WW + tx - 1;
    }

    auto dma_tile = [&](int tt) {
        int gx0n = (bx0 + tt)*32;
        #pragma unroll
        for (int i = 0; i < 7; ++i) {
            int k = wid + 4*i;
            if (k < 27)
                __builtin_amdgcn_global_load_lds((const void*)(imgb + PRE[i] + gx0n),
                                                 (void*)&s_buf[k*256], 16, 0, 0);
        }
        #pragma unroll
        for (int i = 0; i < 2; ++i) {
            int k = wid + 4*i;
            if (k*64 + lane < 340)
                __builtin_amdgcn_global_load_lds((const void*)(dpb + PRED[i] + gx0n),
                                                 (void*)&s_depth[tt & 1][k*64], 4, 0, 0);
        }
    };

    if (bx0 != 0) dma_tile(0);           // prologue (skip if tile0 is x-border)

    for (int t = 0; t < NTILES; ++t) {
        const int bx  = bx0 + t;
        const int gx0 = bx*32;
        const int cur = t & 1;
        const bool border = (bx == 0) || (bx == 19);

        __syncthreads();   // B1: DMA(t) drained; conv2(t-1) done with s_h1/s_depth

        // ---- phase 2a: gather tile into regs (LDS fp32 path or global border path) ----
        short8 vv[4]; float pd0 = 0.f, pd1 = 0.f;
        if (!border) {
            #pragma unroll
            for (int j = 0; j < 4; ++j) {
                int g = tid + j*NT;
                if (g < 864) {
                    int px = g >> 1, half = g & 1;
                    int iy = px / 36;
                    float m = ((unsigned)(gy0 + iy - 2) < HH) ? 1.f : 0.f;
                    #pragma unroll
                    for (int cc = 0; cc < 8; ++cc) {
                        float v = s_buf[(half*8 + cc)*432 + px];
                        vv[j][cc] = f2bf(m * v);
                    }
                }
            }
        } else {
            #pragma unroll
            for (int j = 0; j < 4; ++j) {
                int g = tid + j*NT;
                if (g < 864) {
                    int px = g >> 1, half = g & 1;
                    int iy = px / 36, ix = px - 36*iy;
                    int gy = gy0 + iy - 2, gx = gx0 + ix - 2;
                    bool v = ((unsigned)gy < HH) && ((unsigned)gx < WW);
                    int cy = min(max(gy, 0), HH-1), cx = min(max(gx, 0), WW-1);
                    const float* p = imgb + (size_t)(half*8)*HW + cy*WW + cx;
                    float m = v ? 1.f : 0.f;
                    #pragma unroll
                    for (int cc = 0; cc < 8; ++cc) vv[j][cc] = f2bf(m * p[cc*HW]);
                }
            }
            {
                int ty = tid / 34, tx = tid - 34*ty;
                pd0 = dpb[min(max(gy0 + ty - 1, 0), HH-1)*WW + min(max(gx0 + tx - 1, 0), WW-1)];
            }
            if (tid < 84) {
                int i1 = tid + 256;
                int ty = i1 / 34, tx = i1 - 34*ty;
                pd1 = dpb[min(max(gy0 + ty - 1, 0), HH-1)*WW + min(max(gx0 + tx - 1, 0), WW-1)];
            }
        }

        __syncthreads();   // B2: WAR — all fp32 reads done before bf16 overlay writes

        // ---- phase 2b: write bf16 tile (+ depth for border tiles) ----
        #pragma unroll
        for (int j = 0; j < 4; ++j) {
            int g = tid + j*NT;
            if (g < 864)
                *(short8*)&s_img[(g & 1)*IMPLANE + (g >> 1)*8] = vv[j];
        }
        if (border) {
            s_depth[cur][tid] = pd0;
            if (tid < 84) s_depth[cur][tid + 256] = pd1;
        }

        __syncthreads();   // B3: staging visible

        // ---- conv1 (32x32x16 MFMA, 9 taps + bias tap) -> s_h1 (34-stride planes) ----
        {
            const int oc = lane & 31, cg = lane >> 5;
            short8 a1[10];
            #pragma unroll
            for (int tt = 0; tt < 10; ++tt)
                a1[tt] = *(const short8*)&ws_w1[tt*512 + oc*16 + cg*8];
            short8 bb = (short8)0;               // bias-tap B: one-hot 1.0 at k==0
            bb[0] = (cg == 0) ? (short)0x3F80 : (short)0;

            const int OFS1[9] = {0, 8, 16, 288, 296, 304, 576, 584, 592};
            const int pxl = lane & 31;

            #pragma unroll
            for (int gi = 0; gi < 3; ++gi) {
                int g    = wid + gi*4;
                int hp   = g*32 + pxl;
                int bofs = cg*IMPLANE + hp*8;
                f32x16 acc;
                #pragma unroll
                for (int i = 0; i < 16; ++i) acc[i] = 0.f;
                acc = __builtin_amdgcn_mfma_f32_32x32x16_bf16(a1[9], bb, acc, 0, 0, 0);
                #pragma unroll
                for (int tt = 0; tt < 9; ++tt)
                    acc = __builtin_amdgcn_mfma_f32_32x32x16_bf16(
                             a1[tt], *(const short8*)&s_img[bofs + OFS1[tt]], acc, 0, 0, 0);

                if (hp < 360) {
                    unsigned hy = (unsigned)hp / 36u;
                    int hx = hp - (int)hy*36;
                    if (hx < 34) {
                        int gy = gy0 + (int)hy - 1, gx = gx0 + hx - 1;
                        bool inb = ((unsigned)gy < HH) && ((unsigned)gx < WW);
                        #pragma unroll
                        for (int q = 0; q < 4; ++q) {      // plane q = channels 8q..8q+7
                            short4v h;
                            #pragma unroll
                            for (int j = 0; j < 4; ++j) {
                                float hv = fmaxf(acc[q*4 + j], 0.f);
                                h[j] = inb ? f2bf(hv) : (short)0;
                            }
                            *(short4v*)&s_h1[q*H1PLANE + ((int)hy*34 + hx)*8 + 4*cg] = h;
                        }
                    }
                }
            }
        }
        __syncthreads();   // B4: h1 visible; s_buf free for next DMA

        if (t < NTILES-1 && (bx + 1) != 19) dma_tile(t + 1);  // flies under conv2

        // ---- conv2 (16x16x32 MFMA) + softmax + depth gather ----
        {
            const int fl = lane & 15, cg2 = lane >> 4;
            short8 a2[9];
            #pragma unroll
            for (int tt = 0; tt < 9; ++tt)
                a2[tt] = *(const short8*)&ws_w2[tt*512 + fl*32 + cg2*8];

            const int r0 = 2*wid;                // this wave's output rows r0, r0+1

            #pragma unroll
            for (int chh = 0; chh < 2; ++chh) {  // column halves 0-15, 16-31
                const int ox0 = chh*16;
                const int colbase = cg2*H1PLANE + (ox0 + fl)*8;

                short8 F[4][3];                  // h1 rows r0..r0+3, dx 0..2
                #pragma unroll
                for (int i = 0; i < 4; ++i)
                    #pragma unroll
                    for (int dx = 0; dx < 3; ++dx)
                        F[i][dx] = *(const short8*)&s_h1[colbase + ((r0 + i)*34 + dx)*8];

                f32x4 acc0, acc1;
                #pragma unroll
                for (int i = 0; i < 4; ++i) { acc0[i] = 0.f; acc1[i] = 0.f; }
                #pragma unroll
                for (int i = 0; i < 3; ++i)
                    #pragma unroll
                    for (int dx = 0; dx < 3; ++dx)
                        acc0 = __builtin_amdgcn_mfma_f32_16x16x32_bf16(
                                 a2[i*3 + dx], F[i][dx], acc0, 0, 0, 0);
                #pragma unroll
                for (int i = 0; i < 3; ++i)
                    #pragma unroll
                    for (int dx = 0; dx < 3; ++dx)
                        acc1 = __builtin_amdgcn_mfma_f32_16x16x32_bf16(
                                 a2[i*3 + dx], F[i + 1][dx], acc1, 0, 0, 0);

                #pragma unroll
                for (int rr = 0; rr < 2; ++rr) {
                    f32x4 lg = rr ? acc1 : acc0;
                    int oy = r0 + rr, ox = ox0 + fl;
                    float num = 0.f, den = 0.f;
                    #pragma unroll
                    for (int q = 0; q < 4; ++q) {
                        int f = cg2*4 + q;           // conv2 output channel
                        if (f < 9) {
                            float e = __expf(lg[q]);
                            int fy = f/3, fx = f - fy*3;
                            float d = s_depth[cur][(oy + fy)*34 + (ox + fx)];
                            den += e; num += e * d;
                        }
                    }
                    num += __shfl_xor(num, 16); den += __shfl_xor(den, 16);
                    num += __shfl_xor(num, 32); den += __shfl_xor(den, 32);
                    if (cg2 == 0)
                        out[(size_t)bz*HW + (size_t)(gy0 + oy)*WW + (gx0 + ox)] = num / den;
                }
            }
        }
    }
}

extern "C" void kernel_launch(void* const* d_in, const int* in_sizes, int n_in,
                              void* d_out, int out_size, void* d_ws, size_t ws_size,
                              hipStream_t stream) {
    const float* depth = (const float*)d_in[0];
    const float* img   = (const float*)d_in[1];
    const float* w1    = (const float*)d_in[2];
    const float* b1    = (const float*)d_in[3];
    const float* gamma = (const float*)d_in[4];
    const float* beta  = (const float*)d_in[5];
    const float* rmean = (const float*)d_in[6];
    const float* rvar  = (const float*)d_in[7];
    const float* w2    = (const float*)d_in[8];
    float* out = (float*)d_out;

    short* ws_w1 = (short*)d_ws;          // 5120 shorts (10 taps x 512)
    short* ws_w2 = ws_w1 + 5120;          // 4608 shorts

    prep_weights<<<16, 256, 0, stream>>>(w1, b1, gamma, beta, rmean, rvar, w2,
                                         ws_w1, ws_w2);
    fastprop_main<<<1024, NT, 0, stream>>>(depth, img, ws_w1, ws_w2, out);
}